// Round 10
// baseline (253.478 us; speedup 1.0000x reference)
//
#include <hip/hip_runtime.h>

typedef _Float16 half8_t __attribute__((ext_vector_type(8)));
typedef _Float16 half4_t __attribute__((ext_vector_type(4)));
typedef float    float4_t __attribute__((ext_vector_type(4)));

#define DIM 768

// async global->LDS, 16B per lane; LDS dest is wave-uniform base + lane*16
#define GLOAD16(g, l) __builtin_amdgcn_global_load_lds(                        \
    (const __attribute__((address_space(1))) void*)(g),                        \
    (__attribute__((address_space(3))) void*)(l), 16, 0, 0)

#define MFMA16(a, b, c) __builtin_amdgcn_mfma_f32_16x16x32_f16((a), (b), (c), 0, 0, 0)

// ---------------------------------------------------------------------------
// one fused cast launch: xq (3,145,728 half8) | xkv (786,432) | weights
// (4 x 73,728; dests contiguous in ws starting at Wq16)
// ---------------------------------------------------------------------------
__global__ __launch_bounds__(256) void cast_all(
    const float* __restrict__ xq,  const float* __restrict__ xkv,
    const float* __restrict__ Wq,  const float* __restrict__ Wk,
    const float* __restrict__ Wv,  const float* __restrict__ Wo,
    _Float16* __restrict__ dq, _Float16* __restrict__ dkv,
    _Float16* __restrict__ dW /* 4 matrices contiguous */)
{
    int i = blockIdx.x * 256 + threadIdx.x;    // grid 16512*256 = 4,227,072
    const float* s; _Float16* d; int off;
    if (i < 3145728)      { s = xq;  d = dq;  off = i; }
    else if (i < 3932160) { s = xkv; d = dkv; off = i - 3145728; }
    else {
        int j = i - 3932160;                   // 0..294911
        int w = j / 73728;  off = j - w * 73728;
        s = (w == 0) ? Wq : (w == 1) ? Wk : (w == 2) ? Wv : Wo;
        d = dW + (size_t)w * 589824;
    }
    float4_t f0 = *(const float4_t*)&s[(size_t)off * 8];
    float4_t f1 = *(const float4_t*)&s[(size_t)off * 8 + 4];
    half8_t h;
    #pragma unroll
    for (int e = 0; e < 4; ++e) { h[e] = (_Float16)f0[e]; h[e + 4] = (_Float16)f1[e]; }
    *(half8_t*)&d[(size_t)off * 8] = h;
}

// ---------------------------------------------------------------------------
// GEMM core — r4's measured-best CADENCE (3 slots, stage t+2 during t,
// counted vmcnt never 0 until tail, 2 phases + setprio, same barriers),
// re-geometried for LDS economy:
//   Tile 256x256, BK=32, 24 K-tiles, 512 thr = 8 waves (2M x 4N),
//   per-wave C 128x64 (acc[8][4]) -> 12 b128-reads : 32 MFMA per wave-tile
//   (r9 was 20 : 32) -- halves the per-FLOP LDS-pipe load that capped
//   MfmaUtil at ~24% (LDS is CU-shared, ~12cy/b128).
// LDS: 3 slots x 32KB = 96KB (1 block/CU). Slot = A 16 chunks + B 16 chunks;
// chunk = 1KB = 16 rows x 32 halves, granule-transposed (16B-slot g holds
// row=g&15, koct=g>>4): frag read = chunk_base + lane*16B, contiguous 1KB
// per wave, 0 bank conflicts, exact MFMA fragment layout (proven r5-r9).
// Staging: wave wid owns A chunks {2wid,2wid+1}, B chunks {2wid,2wid+1};
// 4 gload_lds/thread/tile. Boundary wait vmcnt(4) = tile t+1 landed while
// t+2's 4 loads stay in flight; load->wait distance = one full tile
// (~1100cy+) > worst-case HBM latency (fixes r5's BK=32 failure mode).
// ---------------------------------------------------------------------------
__device__ __forceinline__ void gemm_core(const _Float16* __restrict__ A,
                                          const _Float16* __restrict__ W,
                                          int row0, int col0,
                                          _Float16* lds, float4_t acc[8][4])
{
    const int tid  = threadIdx.x;
    const int wid  = tid >> 6, lane = tid & 63;
    const int wr   = wid >> 2;            // 0..1 : 128-row half
    const int wc   = wid & 3;             // 0..3 : 64-col quarter

    // per-lane global staging address: chunk c -> row 16c+(lane&15), k-octet lane>>4
    const int srow = 2 * wid * 16 + (lane & 15);
    const int sk   = (lane >> 4) * 8;
    const _Float16* As0 = A + (size_t)(row0 + srow) * DIM + sk;
    const _Float16* As1 = As0 + (size_t)16 * DIM;
    const _Float16* Bs0 = W + (size_t)(col0 + srow) * DIM + sk;
    const _Float16* Bs1 = Bs0 + (size_t)16 * DIM;

#define STAGE_A(t, s) do {                                                     \
        GLOAD16(As0 + (t) * 32, &lds[(s) * 16384 + (2*wid    ) * 512]);        \
        GLOAD16(As1 + (t) * 32, &lds[(s) * 16384 + (2*wid + 1) * 512]);        \
    } while (0)
#define STAGE_B(t, s) do {                                                     \
        GLOAD16(Bs0 + (t) * 32, &lds[(s) * 16384 + 8192 + (2*wid    ) * 512]); \
        GLOAD16(Bs1 + (t) * 32, &lds[(s) * 16384 + 8192 + (2*wid + 1) * 512]); \
    } while (0)

    const int ab = (wr * 8) * 512 + lane * 8;        // + mi*512
    const int bb = 8192 + (wc * 4) * 512 + lane * 8; // + ni*512

    // ---- prologue: tile0 -> slot0, tile1 -> slot1 ----
    STAGE_A(0, 0); STAGE_B(0, 0);
    STAGE_A(1, 1); STAGE_B(1, 1);
    asm volatile("s_waitcnt vmcnt(4)" ::: "memory");   // tile0 landed
    __builtin_amdgcn_s_barrier();

    int s = 0, s2 = 2;
    for (int t = 0; t < 24; ++t) {
        const _Float16* sl = &lds[s * 16384];
        const bool pf = (t < 22);

        // ================= phase 0 : mi 0..3 =================
        half8_t bf[4], af[4];
        #pragma unroll
        for (int ni = 0; ni < 4; ++ni)
            bf[ni] = *(const half8_t*)&sl[bb + ni * 512];
        #pragma unroll
        for (int mi = 0; mi < 4; ++mi)
            af[mi] = *(const half8_t*)&sl[ab + mi * 512];
        if (pf) STAGE_A(t + 2, s2);
        __builtin_amdgcn_s_barrier();
        asm volatile("s_waitcnt lgkmcnt(0)" ::: "memory");
        __builtin_amdgcn_sched_barrier(0);
        __builtin_amdgcn_s_setprio(1);
        #pragma unroll
        for (int mi = 0; mi < 4; ++mi)
            #pragma unroll
            for (int ni = 0; ni < 4; ++ni)
                acc[mi][ni] = MFMA16(af[mi], bf[ni], acc[mi][ni]);
        __builtin_amdgcn_s_setprio(0);
        __builtin_amdgcn_sched_barrier(0);
        __builtin_amdgcn_s_barrier();

        // ================= phase 1 : mi 4..7 =================
        half8_t af1[4];
        #pragma unroll
        for (int mi = 0; mi < 4; ++mi)
            af1[mi] = *(const half8_t*)&sl[ab + (4 + mi) * 512];
        if (pf) STAGE_B(t + 2, s2);
        __builtin_amdgcn_s_barrier();
        asm volatile("s_waitcnt lgkmcnt(0)" ::: "memory");
        __builtin_amdgcn_sched_barrier(0);
        __builtin_amdgcn_s_setprio(1);
        #pragma unroll
        for (int mi = 0; mi < 4; ++mi)
            #pragma unroll
            for (int ni = 0; ni < 4; ++ni)
                acc[4 + mi][ni] = MFMA16(af1[mi], bf[ni], acc[4 + mi][ni]);
        __builtin_amdgcn_s_setprio(0);
        __builtin_amdgcn_sched_barrier(0);

        // ---- tile boundary: counted vmcnt (T4), full drain only at tail ----
        if (t < 23) {
            if (pf) asm volatile("s_waitcnt vmcnt(4)" ::: "memory");
            else    asm volatile("s_waitcnt vmcnt(0)" ::: "memory");
            __builtin_amdgcn_s_barrier();
        }
        s  = (s  == 2) ? 0 : s  + 1;
        s2 = (s2 == 2) ? 0 : s2 + 1;
    }
#undef STAGE_A
#undef STAGE_B
}

// ---------------------------------------------------------------------------
// Fused q/k/v projection: 576 blocks (256-row x 256-col tiles).
//   bid <  384 : q = elu1(xq @ Wq.T)   (128 row-blocks x 3)
//   384..479   : k = elu1(xkv @ Wk.T)  ( 32 row-blocks x 3)
//   480..575   : v =      xkv @ Wv.T
// ---------------------------------------------------------------------------
__global__ __launch_bounds__(512) void proj_qkv(
    const _Float16* __restrict__ xq16, const _Float16* __restrict__ xkv16,
    const _Float16* __restrict__ Wq16, const _Float16* __restrict__ Wk16,
    const _Float16* __restrict__ Wv16,
    _Float16* __restrict__ q16, _Float16* __restrict__ k16,
    _Float16* __restrict__ v16)
{
    __shared__ __align__(16) _Float16 lds[3 * 16384];   // 98304 B

    const int cpx = gridDim.x >> 3;                     // 576/8 = 72
    int bid = (blockIdx.x & 7) * cpx + (blockIdx.x >> 3);

    const _Float16 *A, *W; _Float16* O; bool elu;
    int brow, bcol;
    if (bid < 384) {
        A = xq16; W = Wq16; O = q16; elu = true;
        brow = bid / 3; bcol = bid - brow * 3;
    } else {
        int u = bid - 384;
        int mat = u / 96;  u -= mat * 96;
        A = xkv16; W = mat ? Wv16 : Wk16; O = mat ? v16 : k16; elu = !mat;
        brow = u / 3; bcol = u - brow * 3;
    }
    const int row0 = brow * 256, col0 = bcol * 256;

    float4_t acc[8][4] = {};
    gemm_core(A, W, row0, col0, lds, acc);

    const int wid = threadIdx.x >> 6, lane = threadIdx.x & 63;
    const int wr = wid >> 2, wc = wid & 3, lr = lane & 15, lkg = lane >> 4;
    #pragma unroll
    for (int mi = 0; mi < 8; ++mi) {
        #pragma unroll
        for (int ni = 0; ni < 4; ++ni) {
            #pragma unroll
            for (int e = 0; e < 4; ++e) {
                int r = row0 + wr * 128 + mi * 16 + lkg * 4 + e;
                int c = col0 + wc * 64 + ni * 16 + lr;
                float v = acc[mi][ni][e];
                if (elu) v = (v > 0.0f) ? (v + 1.0f) : __expf(v);  // elu(x)+1
                O[(size_t)r * DIM + c] = (_Float16)v;
            }
        }
    }
}

// ---------------------------------------------------------------------------
// out = attn16 @ Wo.T + bo  (fp32 output), 384 blocks
// ---------------------------------------------------------------------------
__global__ __launch_bounds__(512) void out_proj(
    const _Float16* __restrict__ a16, const _Float16* __restrict__ Wo16,
    const float* __restrict__ bo, float* __restrict__ out)
{
    __shared__ __align__(16) _Float16 lds[3 * 16384];

    const int cpx = gridDim.x >> 3;                     // 384/8 = 48
    int bid = (blockIdx.x & 7) * cpx + (blockIdx.x >> 3);
    const int brow = bid / 3, bcol = bid - brow * 3;
    const int row0 = brow * 256, col0 = bcol * 256;

    float4_t acc[8][4] = {};
    gemm_core(a16, Wo16, row0, col0, lds, acc);

    const int wid = threadIdx.x >> 6, lane = threadIdx.x & 63;
    const int wr = wid >> 2, wc = wid & 3, lr = lane & 15, lkg = lane >> 4;
    #pragma unroll
    for (int mi = 0; mi < 8; ++mi) {
        #pragma unroll
        for (int ni = 0; ni < 4; ++ni) {
            #pragma unroll
            for (int e = 0; e < 4; ++e) {
                int r = row0 + wr * 128 + mi * 16 + lkg * 4 + e;
                int c = col0 + wc * 64 + ni * 16 + lr;
                out[(size_t)r * DIM + c] = acc[mi][ni][e] + bo[c];
            }
        }
    }
}

// ---------------------------------------------------------------------------
// kv_reduce: per (b,h): kvh[e][d] = sum_n v[n,e]*k[n,d];  ksum[d] = sum_n k[n,d]
// ---------------------------------------------------------------------------
__global__ __launch_bounds__(256) void kv_reduce(const _Float16* __restrict__ k16,
                                                 const _Float16* __restrict__ v16,
                                                 float* __restrict__ kvh,
                                                 float* __restrict__ ksum)
{
    __shared__ __align__(16) _Float16 K[128][64];
    __shared__ __align__(16) _Float16 V[128][64];
    const int chunk = blockIdx.x;   // 0..7
    const int bh    = blockIdx.y;   // 0..95
    const int b = bh / 12, h = bh % 12;
    const int tid = threadIdx.x;

    const size_t base = ((size_t)b * 1024 + (size_t)chunk * 128) * DIM + h * 64;
    #pragma unroll
    for (int j = 0; j < 4; ++j) {
        int idx = j * 256 + tid;
        int r = idx >> 3, c = (idx & 7) * 8;
        *(half8_t*)&K[r][c] = *(const half8_t*)&k16[base + (size_t)r * DIM + c];
        *(half8_t*)&V[r][c] = *(const half8_t*)&v16[base + (size_t)r * DIM + c];
    }
    __syncthreads();

    const int d0 = (tid & 15) * 4;
    const int e0 = (tid >> 4) * 4;
    float acc[4][4] = {};
    #pragma unroll 4
    for (int n = 0; n < 128; ++n) {
        half4_t kd = *(const half4_t*)&K[n][d0];
        half4_t ve = *(const half4_t*)&V[n][e0];
        #pragma unroll
        for (int i = 0; i < 4; ++i)
            #pragma unroll
            for (int j = 0; j < 4; ++j)
                acc[i][j] += (float)ve[i] * (float)kd[j];
    }
    float* kvp = kvh + (size_t)bh * 64 * 64;
    #pragma unroll
    for (int i = 0; i < 4; ++i)
        #pragma unroll
        for (int j = 0; j < 4; ++j)
            atomicAdd(&kvp[(e0 + i) * 64 + d0 + j], acc[i][j]);

    if (tid < 64) {
        float s = 0.0f;
        for (int n = 0; n < 128; ++n) s += (float)K[n][tid];
        atomicAdd(&ksum[bh * 64 + tid], s);
    }
}

// ---------------------------------------------------------------------------
// attn: z = 1/(q . ksum + 1e-6); attn = (q @ kv) * z   (in-place on q16)
// ---------------------------------------------------------------------------
__global__ __launch_bounds__(256) void attn_kernel(_Float16* __restrict__ q16,
                                                   const float* __restrict__ kvh,
                                                   const float* __restrict__ ksum)
{
    __shared__ __align__(16) _Float16 Q[128][72];
    __shared__ __align__(16) _Float16 Bv[64][72];
    __shared__ float S[64];
    __shared__ float Z[128];

    const int h    = blockIdx.x;        // 0..11
    const int rb   = blockIdx.y;        // 0..255
    const int row0 = rb * 128;
    const int b    = row0 >> 12;
    const int bh   = b * 12 + h;
    const int tid  = threadIdx.x;

    #pragma unroll
    for (int j = 0; j < 4; ++j) {
        int idx = j * 256 + tid;
        int r = idx >> 3, c = (idx & 7) * 8;
        *(half8_t*)&Q[r][c] =
            *(const half8_t*)&q16[(size_t)(row0 + r) * DIM + h * 64 + c];
    }
    #pragma unroll
    for (int j = 0; j < 4; ++j) {
        int idx = j * 256 + tid;
        int r = idx >> 4, c = (idx & 15) * 4;
        float4_t f = *(const float4_t*)&kvh[((size_t)bh * 64 + r) * 64 + c];
        half4_t hh;
        #pragma unroll
        for (int e = 0; e < 4; ++e) hh[e] = (_Float16)f[e];
        *(half4_t*)&Bv[r][c] = hh;
    }
    if (tid < 64) S[tid] = ksum[bh * 64 + tid];
    __syncthreads();

    if (tid < 128) {
        float dot = 0.0f;
        #pragma unroll 8
        for (int d = 0; d < 64; ++d) dot += (float)Q[tid][d] * S[d];
        Z[tid] = 1.0f / (dot + 1e-6f);
    }
    __syncthreads();

    const int w = tid >> 6, lane = tid & 63;
    const int lr = lane & 15, lkg = lane >> 4;
    float4_t acc[2][4] = {};
    #pragma unroll
    for (int kc = 0; kc < 2; ++kc) {
        half8_t aF[2], bF[4];
        #pragma unroll
        for (int mi = 0; mi < 2; ++mi)
            aF[mi] = *(const half8_t*)&Q[w * 32 + mi * 16 + lr][kc * 32 + lkg * 8];
        #pragma unroll
        for (int ni = 0; ni < 4; ++ni)
            bF[ni] = *(const half8_t*)&Bv[ni * 16 + lr][kc * 32 + lkg * 8];
        #pragma unroll
        for (int mi = 0; mi < 2; ++mi)
            #pragma unroll
            for (int ni = 0; ni < 4; ++ni)
                acc[mi][ni] = MFMA16(aF[mi], bF[ni], acc[mi][ni]);
    }
    #pragma unroll
    for (int mi = 0; mi < 2; ++mi) {
        #pragma unroll
        for (int ni = 0; ni < 4; ++ni) {
            #pragma unroll
            for (int e = 0; e < 4; ++e) {
                int r = w * 32 + mi * 16 + lkg * 4 + e;
                float v = acc[mi][ni][e] * Z[r];
                q16[(size_t)(row0 + r) * DIM + h * 64 + ni * 16 + lr] = (_Float16)v;
            }
        }
    }
}

// ---------------------------------------------------------------------------
extern "C" void kernel_launch(void* const* d_in, const int* in_sizes, int n_in,
                              void* d_out, int out_size, void* d_ws, size_t ws_size,
                              hipStream_t stream)
{
    const float* xq  = (const float*)d_in[0];  // [8,4096,768]
    const float* xkv = (const float*)d_in[1];  // [8,1024,768]
    const float* Wq  = (const float*)d_in[2];
    const float* Wk  = (const float*)d_in[3];
    const float* Wv  = (const float*)d_in[4];
    const float* Wo  = (const float*)d_in[5];
    const float* bo  = (const float*)d_in[6];

    // ---- workspace layout (~69 MB) ----
    char* ws = (char*)d_ws;
    const size_t SZ_Q16   = (size_t)32768 * 768 * 2;   // 50,331,648
    const size_t SZ_XKV16 = (size_t)8192 * 768 * 2;    // 12,582,912
    const size_t SZ_W16   = (size_t)768 * 768 * 2;     //  1,179,648
    const size_t SZ_KVH   = (size_t)96 * 64 * 64 * 4;  //  1,572,864
    const size_t SZ_KSUM  = (size_t)96 * 64 * 4;       //     24,576

    _Float16* q16   = (_Float16*)(ws);
    _Float16* xkv16 = (_Float16*)(ws + SZ_Q16);
    _Float16* Wq16  = (_Float16*)(ws + SZ_Q16 + SZ_XKV16);            // 4 contiguous
    _Float16* Wk16  = (_Float16*)(ws + SZ_Q16 + SZ_XKV16 + SZ_W16);
    _Float16* Wv16  = (_Float16*)(ws + SZ_Q16 + SZ_XKV16 + 2 * SZ_W16);
    _Float16* Wo16  = (_Float16*)(ws + SZ_Q16 + SZ_XKV16 + 3 * SZ_W16);
    float*    kvh   = (float*)   (ws + SZ_Q16 + SZ_XKV16 + 4 * SZ_W16);
    float*    ksum  = (float*)   (ws + SZ_Q16 + SZ_XKV16 + 4 * SZ_W16 + SZ_KVH);

    // ---- d_out aliasing: xq16 consumed by proj_qkv; k16/v16 by kv_reduce;
    //      all dead before out_proj overwrites d_out. ----
    char* ob = (char*)d_out;
    _Float16* xq16 = (_Float16*)(ob);                       // 50,331,648
    _Float16* k16  = (_Float16*)(ob + 50331648);            // 12,582,912
    _Float16* v16  = (_Float16*)(ob + 50331648 + 12582912); // 12,582,912
    float*    out  = (float*)d_out;

    // 1) one fused cast launch + kv accumulator clear
    cast_all<<<16512, 256, 0, stream>>>(xq, xkv, Wq, Wk, Wv, Wo,
                                        xq16, xkv16, Wq16);
    hipMemsetAsync(kvh, 0, SZ_KVH + SZ_KSUM, stream);

    // 2) fused projections: q = elu1(xq@Wq.T), k = elu1(xkv@Wk.T), v = xkv@Wv.T
    proj_qkv<<<576, 512, 0, stream>>>(xq16, xkv16, Wq16, Wk16, Wv16,
                                      q16, k16, v16);

    // 3) linear attention
    kv_reduce<<<dim3(8, 96), 256, 0, stream>>>(k16, v16, kvh, ksum);
    attn_kernel<<<dim3(12, 256), 256, 0, stream>>>(q16, kvh, ksum);

    // 4) out = attn @ Wo.T + bo  (fp32 output)
    out_proj<<<384, 512, 0, stream>>>(q16, Wo16, bo, out);
}